// Round 1
// baseline (260.848 us; speedup 1.0000x reference)
//
#include <hip/hip_runtime.h>
#include <stdint.h>
#include <math.h>

#define TT 128
#define CC 600
#define HH 75

typedef __attribute__((ext_vector_type(8)))  short bh8;
typedef __attribute__((ext_vector_type(16))) float f32x16;
typedef __attribute__((ext_vector_type(4)))  float f32x4;

// ---- LDS layout (bytes) ----
// phase 1 staging: XA[2] @0 (2*10240), WB[2] @20480 (2*20480)  -> [0,61440)
// phase 2+ (alias): P @0 (32768), PM @32768 (1024), PS @33792 (1024)
// persistent:       Q @61440 (32768), K @94208 (32768), VT @126976 (20480) -> 147456
#define XA_OFF   0
#define WB_OFF   20480
#define P_OFF    0
#define PM_OFF   32768
#define PS_OFF   33792
#define Q_OFF    61440
#define K_OFF    94208
#define V_OFF    126976
#define LDS_BYTES 147456

__device__ __forceinline__ uint32_t f2bf1(float f) {
  uint32_t u = __float_as_uint(f);
  return (u + 0x7FFFu + ((u >> 16) & 1u)) >> 16;   // RNE f32->bf16
}
__device__ __forceinline__ uint32_t packbf(float a, float b) {
  return f2bf1(a) | (f2bf1(b) << 16);
}
__device__ __forceinline__ float bfrt(float f) {   // bf16 round-trip
  return __uint_as_float(f2bf1(f) << 16);
}
// 256B-stride rows, XOR-swizzle the 16B-slot index (bits 4..6) by row&7
__device__ __forceinline__ int swz(int row, int bytein) {
  return row * 256 + (bytein ^ ((row & 7) << 4));
}

// ---------------- prepass: pack W into bf16, [chunk][n(256)][kslot(40)] ----------------
// n = sec*80 + h (sec 0=q,1=k,2=v; h<75 valid), kslot s<32: k=chunk*32+s, rest zero.
__global__ void pack_w_kernel(const float* __restrict__ Wq, const float* __restrict__ Wk,
                              const float* __restrict__ Wv, uint16_t* __restrict__ wpack) {
  const int chunk = blockIdx.x;   // 0..18
  const int n     = threadIdx.x;  // 0..255
  const float* W = nullptr;
  int h = 0;
  if (n < 80)       { W = Wq; h = n; }
  else if (n < 160) { W = Wk; h = n - 80; }
  else if (n < 240) { W = Wv; h = n - 160; }
  const bool valid = (W != nullptr) && (h < 75);
  uint32_t u[20];
#pragma unroll
  for (int g = 0; g < 20; ++g) u[g] = 0u;
#pragma unroll
  for (int s = 0; s < 32; ++s) {
    const int k = chunk * 32 + s;
    float v = 0.f;
    if (valid && k < CC) v = W[k * HH + h];
    u[s >> 1] |= f2bf1(v) << ((s & 1) * 16);
  }
  uint32_t* dst = (uint32_t*)(wpack + (size_t)chunk * 10240 + (size_t)n * 40);
#pragma unroll
  for (int g = 0; g < 5; ++g)
    ((uint4*)dst)[g] = make_uint4(u[g*4], u[g*4+1], u[g*4+2], u[g*4+3]);
}

// ---------------- main: fused qkv-projection + causal attention, one WG per batch ----------------
__global__ __launch_bounds__(512, 2) void head_kernel(
    const float* __restrict__ x, const uint16_t* __restrict__ wpack,
    float* __restrict__ out)
{
  __shared__ char smem[LDS_BYTES];
  const int tid  = threadIdx.x;
  const int b    = blockIdx.x;
  const int lane = tid & 63;
  const int wv   = tid >> 6;      // wave 0..7
  const int l31  = lane & 31;
  const int h5   = lane >> 5;

  //========================= phase 1: [128x600]@[600x240] -> q,k,v =========================
  const int m0 = (wv >> 2) * 64;  // wave tile: 64x64
  const int n0 = (wv & 3) * 64;

  f32x16 acc[2][2];
#pragma unroll
  for (int mi = 0; mi < 2; ++mi)
#pragma unroll
    for (int ni = 0; ni < 2; ++ni)
#pragma unroll
      for (int r = 0; r < 16; ++r) acc[mi][ni][r] = 0.f;

  const int xt  = tid >> 2;       // x row 0..127
  const int xcg = tid & 3;        // 8-float group
  const float* xrow = x + (size_t)b * (TT * CC) + (size_t)xt * CC;

  { // prologue: stage chunk 0 into buffer 0
    float4 p0 = *(const float4*)(xrow + xcg * 4);
    float4 p1 = *(const float4*)(xrow + 16 + xcg * 4);
    const uint4* wc = (const uint4*)wpack;
    uint4 q0 = wc[tid];
    uint4 q1 = wc[tid + 512];
    uint4 q2 = make_uint4(0,0,0,0);
    if (tid < 256) q2 = wc[tid + 1024];
    char* xa = smem + XA_OFF;
    char* wb = smem + WB_OFF;
    *(uint2*)(xa + xt * 80 + xcg * 8)      = make_uint2(packbf(p0.x, p0.y), packbf(p0.z, p0.w));
    *(uint2*)(xa + xt * 80 + 32 + xcg * 8) = make_uint2(packbf(p1.x, p1.y), packbf(p1.z, p1.w));
    *(uint4*)(wb + tid * 16)          = q0;
    *(uint4*)(wb + (tid + 512) * 16)  = q1;
    if (tid < 256) *(uint4*)(wb + (tid + 1024) * 16) = q2;
    __syncthreads();
  }

  for (int c = 0; c < 19; ++c) {
    const int  buf  = c & 1;
    const bool more = (c + 1 < 19);
    float4 p0, p1; uint4 q0, q1, q2;
    if (more) {  // issue prefetch for chunk c+1 (latency hidden under compute)
      const int cc = c + 1;
      p0 = *(const float4*)(xrow + cc * 32 + xcg * 4);
      const int c2 = cc * 32 + 16 + xcg * 4;
      p1 = *(const float4*)(xrow + ((c2 < CC) ? c2 : 0));  // OOB-safe; hits zero W slots
      const uint4* wc = (const uint4*)(wpack + (size_t)cc * 10240);
      q0 = wc[tid];
      q1 = wc[tid + 512];
      if (tid < 256) q2 = wc[tid + 1024];
    }
    const char* xa = smem + XA_OFF + buf * 10240;
    const char* wb = smem + WB_OFF + buf * 20480;
#pragma unroll
    for (int ks = 0; ks < 2; ++ks) {
      bh8 af[2], bf[2];
#pragma unroll
      for (int mi = 0; mi < 2; ++mi)
        af[mi] = *(const bh8*)(xa + (m0 + mi * 32 + l31) * 80 + ks * 32 + h5 * 16);
#pragma unroll
      for (int ni = 0; ni < 2; ++ni)
        bf[ni] = *(const bh8*)(wb + (n0 + ni * 32 + l31) * 80 + ks * 32 + h5 * 16);
#pragma unroll
      for (int mi = 0; mi < 2; ++mi)
#pragma unroll
        for (int ni = 0; ni < 2; ++ni)
          acc[mi][ni] = __builtin_amdgcn_mfma_f32_32x32x16_bf16(af[mi], bf[ni], acc[mi][ni], 0, 0, 0);
    }
    if (more) {  // write prefetched chunk to the other buffer
      const int nb = buf ^ 1;
      char* xaw = smem + XA_OFF + nb * 10240;
      char* wbw = smem + WB_OFF + nb * 20480;
      *(uint2*)(xaw + xt * 80 + xcg * 8)      = make_uint2(packbf(p0.x, p0.y), packbf(p0.z, p0.w));
      *(uint2*)(xaw + xt * 80 + 32 + xcg * 8) = make_uint2(packbf(p1.x, p1.y), packbf(p1.z, p1.w));
      *(uint4*)(wbw + tid * 16)          = q0;
      *(uint4*)(wbw + (tid + 512) * 16)  = q1;
      if (tid < 256) *(uint4*)(wbw + (tid + 1024) * 16) = q2;
    }
    __syncthreads();
  }

  // epilogue: acc -> bf16 q[t][h], k[t][h], vT[h][t] in LDS (swizzled 256B rows)
#pragma unroll
  for (int mi = 0; mi < 2; ++mi) {
    const int tb = m0 + mi * 32;
#pragma unroll
    for (int ni = 0; ni < 2; ++ni) {
      const int nn = n0 + ni * 32 + l31;
      if (n0 + ni * 32 < 160) {            // q or k section: scalar b16 writes
        char* base  = smem + (nn < 80 ? Q_OFF : K_OFF);
        const int hb = (nn < 80 ? nn : nn - 80) * 2;
#pragma unroll
        for (int r = 0; r < 16; ++r) {
          const int t = tb + (r & 3) + 8 * (r >> 2) + 4 * h5;
          *(uint16_t*)(base + swz(t, hb)) = (uint16_t)f2bf1(acc[mi][ni][r]);
        }
      } else if (nn < 240) {               // v section: transposed packed b64 writes
        const int hh2 = nn - 160;
#pragma unroll
        for (int g = 0; g < 4; ++g) {
          const int t0 = tb + 8 * g + 4 * h5;
          *(uint2*)(smem + V_OFF + swz(hh2, t0 * 2)) =
            make_uint2(packbf(acc[mi][ni][4*g],   acc[mi][ni][4*g+1]),
                       packbf(acc[mi][ni][4*g+2], acc[mi][ni][4*g+3]));
        }
      }
    }
  }
  __syncthreads();

  //========================= phase 2: S^T = K@Q^T, causal softmax =========================
  const int mt2 = wv & 1;                  // s-half (64 keys)
  const int tq  = (wv >> 1) * 32 + l31;    // this lane's query column
  f32x16 sac[2];
#pragma unroll
  for (int ts2 = 0; ts2 < 2; ++ts2)
#pragma unroll
    for (int r = 0; r < 16; ++r) sac[ts2][r] = 0.f;

#pragma unroll
  for (int ks = 0; ks < 5; ++ks) {         // K-dim = 80 (zeros in 75..79)
    const int kb = ks * 32 + h5 * 16;
    const bh8 qf = *(const bh8*)(smem + Q_OFF + swz(tq, kb));
#pragma unroll
    for (int ts2 = 0; ts2 < 2; ++ts2) {
      const int sr = (mt2 * 2 + ts2) * 32 + l31;
      const bh8 kf = *(const bh8*)(smem + K_OFF + swz(sr, kb));
      sac[ts2] = __builtin_amdgcn_mfma_f32_32x32x16_bf16(kf, qf, sac[ts2], 0, 0, 0);
    }
  }

  float pvv[32];
  float vmax = -INFINITY;
  const float scl = 0.040824829046386302f;   // 600^-0.5 (reference uses C, not head_size)
#pragma unroll
  for (int ts2 = 0; ts2 < 2; ++ts2) {
    const int st = (mt2 * 2 + ts2) * 32;
#pragma unroll
    for (int r = 0; r < 16; ++r) {
      const int s = st + (r & 3) + 8 * (r >> 2) + 4 * h5;
      float v = sac[ts2][r] * scl;
      v = (s <= tq) ? v : -INFINITY;
      pvv[ts2 * 16 + r] = v;
      vmax = fmaxf(vmax, v);
    }
  }
  vmax = fmaxf(vmax, __shfl_xor(vmax, 32)); // combine half-waves -> partial over 64 keys
  float* pmb = (float*)(smem + PM_OFF);
  float* psb = (float*)(smem + PS_OFF);
  if (h5 == 0) pmb[mt2 * 128 + tq] = vmax;
  __syncthreads();
  const float mrow = fmaxf(pmb[tq], pmb[128 + tq]);
  float sum = 0.f;
#pragma unroll
  for (int i = 0; i < 32; ++i) {
    const float p = bfrt(__expf(pvv[i] - mrow));  // round to bf16 so denom matches numerator
    pvv[i] = p;
    sum += p;
  }
  sum += __shfl_xor(sum, 32);
  if (h5 == 0) psb[mt2 * 128 + tq] = sum;
  // write P (bf16) into swizzled LDS (aliases dead staging buffers)
#pragma unroll
  for (int ts2 = 0; ts2 < 2; ++ts2) {
    const int st = (mt2 * 2 + ts2) * 32;
#pragma unroll
    for (int g = 0; g < 4; ++g) {
      const int s0 = st + 8 * g + 4 * h5;
      *(uint2*)(smem + P_OFF + swz(tq, s0 * 2)) =
        make_uint2(packbf(pvv[ts2*16+4*g],   pvv[ts2*16+4*g+1]),
                   packbf(pvv[ts2*16+4*g+2], pvv[ts2*16+4*g+3]));
    }
  }
  __syncthreads();

  //========================= phase 3: O = P@V, normalize, store =========================
  const int l15   = lane & 15;
  const int q4    = lane >> 4;
  const int trow0 = wv * 16;               // wave owns 16 query rows
  f32x4 oac[5];
#pragma unroll
  for (int nt = 0; nt < 5; ++nt)
#pragma unroll
    for (int r = 0; r < 4; ++r) oac[nt][r] = 0.f;

#pragma unroll
  for (int ks = 0; ks < 4; ++ks) {         // K-dim = 128 keys
    const int kb = ks * 64 + q4 * 16;
    const bh8 pf = *(const bh8*)(smem + P_OFF + swz(trow0 + l15, kb));
#pragma unroll
    for (int nt = 0; nt < 5; ++nt) {
      const bh8 vf = *(const bh8*)(smem + V_OFF + swz(nt * 16 + l15, kb));
      oac[nt] = __builtin_amdgcn_mfma_f32_16x16x32_bf16(pf, vf, oac[nt], 0, 0, 0);
    }
  }

  const float* psf = (const float*)(smem + PS_OFF);
  float rinv[4];
#pragma unroll
  for (int r = 0; r < 4; ++r) {
    const int t = trow0 + q4 * 4 + r;
    rinv[r] = 1.0f / (psf[t] + psf[128 + t]);
  }
  float* ob = out + (size_t)b * (TT * HH);
#pragma unroll
  for (int nt = 0; nt < 5; ++nt) {
    const int h = nt * 16 + l15;
    if (h < 75) {
#pragma unroll
      for (int r = 0; r < 4; ++r) {
        const int t = trow0 + q4 * 4 + r;
        ob[t * HH + h] = oac[nt][r] * rinv[r];
      }
    }
  }
}

extern "C" void kernel_launch(void* const* d_in, const int* in_sizes, int n_in,
                              void* d_out, int out_size, void* d_ws, size_t ws_size,
                              hipStream_t stream) {
  (void)in_sizes; (void)n_in; (void)out_size; (void)ws_size;
  const float* x  = (const float*)d_in[0];
  const float* Wq = (const float*)d_in[1];
  const float* Wk = (const float*)d_in[2];
  const float* Wv = (const float*)d_in[3];
  uint16_t* wpack = (uint16_t*)d_ws;       // 19*256*40*2 = 389,120 B
  float* out = (float*)d_out;
  pack_w_kernel<<<19, 256, 0, stream>>>(Wq, Wk, Wv, wpack);
  head_kernel<<<512, 512, 0, stream>>>(x, wpack, out);
}

// Round 4
// 249.750 us; speedup vs baseline: 1.0444x; 1.0444x over previous
//
#include <hip/hip_runtime.h>
#include <stdint.h>
#include <math.h>

#define TT 128
#define CC 600
#define HH 75

typedef __attribute__((ext_vector_type(8)))  short bh8;
typedef __attribute__((ext_vector_type(16))) float f32x16;
typedef __attribute__((ext_vector_type(4)))  float f32x4;

// ---- LDS layout (bytes), total 81920 = 80KB -> 2 blocks/CU ----
// phase 1: XA[2] x-staging @0 (2*10240)
// phase 2+ alias: P (one s-half) @0 (16384), PM @16384 (1024), PS @17408 (1024)
// persistent: Q @20480 (20480), K @40960 (20480), VT @61440 (20480)
#define XA_OFF 0
#define P_OFF  0
#define PM_OFF 16384
#define PS_OFF 17408
#define Q_OFF  20480
#define K_OFF  40960
#define V_OFF  61440
#define LDS_BYTES 81920

__device__ __forceinline__ uint32_t f2bf1(float f) {
  uint32_t u = __float_as_uint(f);
  return (u + 0x7FFFu + ((u >> 16) & 1u)) >> 16;   // RNE f32->bf16
}
__device__ __forceinline__ uint32_t packbf(float a, float b) {
  return f2bf1(a) | (f2bf1(b) << 16);
}
__device__ __forceinline__ float bfrt(float f) {   // bf16 round-trip
  return __uint_as_float(f2bf1(f) << 16);
}
// V: 256B-stride rows, XOR-swizzle 16B-slot index by row&7
__device__ __forceinline__ int swz(int row, int bytein) {
  return row * 256 + (bytein ^ ((row & 7) << 4));
}
// P: 128B-stride rows, XOR-swizzle 16B-slot index by row&7
__device__ __forceinline__ int pswz(int row, int bytein) {
  return row * 128 + (bytein ^ ((row & 7) << 4));
}

// ---------------- prepass: pack W as per-lane MFMA B-fragments ----------------
// fragment (cs = c*2+ks, n, h5) = 8 bf16 of column n, k = cs*16 + h5*8 + j.
// n = sec*80 + h (0=q,1=k,2=v); zeros for h>=75, n>=240, k>=600.
__global__ void pack_w_kernel(const float* __restrict__ Wq, const float* __restrict__ Wk,
                              const float* __restrict__ Wv, uint16_t* __restrict__ wpack) {
  const int cs  = blockIdx.x;      // 0..37
  const int tid = threadIdx.x;     // 0..511
  const int n   = tid >> 1;
  const int h5  = tid & 1;
  const int sec = n / 80;
  const int h   = n - sec * 80;
  const float* W = (sec == 0) ? Wq : (sec == 1) ? Wk : (sec == 2) ? Wv : nullptr;
  const bool valid = (W != nullptr) && (h < HH);
  const int k0 = cs * 16 + h5 * 8;
  uint32_t u[4] = {0u, 0u, 0u, 0u};
  if (valid) {
#pragma unroll
    for (int j = 0; j < 8; ++j) {
      const int k = k0 + j;
      float v = (k < CC) ? W[k * HH + h] : 0.f;
      u[j >> 1] |= f2bf1(v) << ((j & 1) * 16);
    }
  }
  ((uint4*)wpack)[cs * 512 + n * 2 + h5] = make_uint4(u[0], u[1], u[2], u[3]);
}

// ---------------- main: fused qkv-projection + causal attention, one WG per batch ----------------
__global__ __launch_bounds__(512, 4) void head_kernel(
    const float* __restrict__ x, const uint16_t* __restrict__ wpack,
    float* __restrict__ out)
{
  __shared__ char smem[LDS_BYTES];
  const int tid  = threadIdx.x;
  const int b    = blockIdx.x;
  const int lane = tid & 63;
  const int wv   = tid >> 6;      // wave 0..7
  const int l31  = lane & 31;
  const int h5   = lane >> 5;

  //========================= phase 1: [128x600]@[600x240] -> q,k,v =========================
  const int m0 = (wv >> 2) * 64;  // wave tile: 64x64
  const int n0 = (wv & 3) * 64;

  f32x16 acc[2][2];
#pragma unroll
  for (int mi = 0; mi < 2; ++mi)
#pragma unroll
    for (int ni = 0; ni < 2; ++ni)
#pragma unroll
      for (int r = 0; r < 16; ++r) acc[mi][ni][r] = 0.f;

  const int xt  = tid >> 2;       // x row 0..127
  const int xcg = tid & 3;        // 8-float group
  const float* xrow = x + (size_t)b * (TT * CC) + (size_t)xt * CC;
  const bh8* wfp = (const bh8*)wpack;       // 16B fragments
  const int woff = (n0 + l31) * 2 + h5;     // lane's fragment offset

  { // prologue: stage chunk 0 into buffer 0
    float4 p0 = *(const float4*)(xrow + xcg * 4);
    float4 p1 = *(const float4*)(xrow + 16 + xcg * 4);
    char* xa = smem + XA_OFF;
    *(uint2*)(xa + xt * 80 + xcg * 8)      = make_uint2(packbf(p0.x, p0.y), packbf(p0.z, p0.w));
    *(uint2*)(xa + xt * 80 + 32 + xcg * 8) = make_uint2(packbf(p1.x, p1.y), packbf(p1.z, p1.w));
    __syncthreads();
  }

  for (int c = 0; c < 19; ++c) {
    const int  buf  = c & 1;
    const bool more = (c + 1 < 19);
    // W B-fragments for THIS chunk, straight from L2 (issued first so the
    // MFMA's vmcnt wait does not drain the x prefetch behind them)
    bh8 w00 = wfp[(c * 2 + 0) * 512 + 0  + woff];
    bh8 w01 = wfp[(c * 2 + 0) * 512 + 64 + woff];
    bh8 w10 = wfp[(c * 2 + 1) * 512 + 0  + woff];
    bh8 w11 = wfp[(c * 2 + 1) * 512 + 64 + woff];
    float4 p0, p1;
    if (more) {  // x prefetch for chunk c+1
      const int cc = c + 1;
      p0 = *(const float4*)(xrow + cc * 32 + xcg * 4);
      const int c2 = cc * 32 + 16 + xcg * 4;
      p1 = *(const float4*)(xrow + ((c2 < CC) ? c2 : 0));  // OOB-safe; hits zero W slots
    }
    const char* xa = smem + XA_OFF + buf * 10240;
#pragma unroll
    for (int ks = 0; ks < 2; ++ks) {
      bh8 af[2];
#pragma unroll
      for (int mi = 0; mi < 2; ++mi)
        af[mi] = *(const bh8*)(xa + (m0 + mi * 32 + l31) * 80 + ks * 32 + h5 * 16);
      const bh8 b0 = ks ? w10 : w00;
      const bh8 b1 = ks ? w11 : w01;
#pragma unroll
      for (int mi = 0; mi < 2; ++mi) {
        acc[mi][0] = __builtin_amdgcn_mfma_f32_32x32x16_bf16(af[mi], b0, acc[mi][0], 0, 0, 0);
        acc[mi][1] = __builtin_amdgcn_mfma_f32_32x32x16_bf16(af[mi], b1, acc[mi][1], 0, 0, 0);
      }
    }
    if (more) {
      const int nb = buf ^ 1;
      char* xaw = smem + XA_OFF + nb * 10240;
      *(uint2*)(xaw + xt * 80 + xcg * 8)      = make_uint2(packbf(p0.x, p0.y), packbf(p0.z, p0.w));
      *(uint2*)(xaw + xt * 80 + 32 + xcg * 8) = make_uint2(packbf(p1.x, p1.y), packbf(p1.z, p1.w));
    }
    __syncthreads();
  }

  // epilogue: acc -> bf16 Q[hg][t][32B], K[hg][t][32B], VT[h][t] (swizzled)
#pragma unroll
  for (int mi = 0; mi < 2; ++mi) {
    const int tb = m0 + mi * 32;
#pragma unroll
    for (int ni = 0; ni < 2; ++ni) {
      const int nn = n0 + ni * 32 + l31;
      if (nn < 160) {                      // q or k section: scalar b16 writes
        const int h = (nn < 80) ? nn : nn - 80;
        char* base = smem + ((nn < 80) ? Q_OFF : K_OFF) + (h >> 4) * 4096 + (h & 15) * 2;
#pragma unroll
        for (int r = 0; r < 16; ++r) {
          const int t = tb + (r & 3) + 8 * (r >> 2) + 4 * h5;
          *(uint16_t*)(base + t * 32) = (uint16_t)f2bf1(acc[mi][ni][r]);
        }
      } else if (nn < 240) {               // v section: transposed packed b64 writes
        const int hh2 = nn - 160;
#pragma unroll
        for (int g = 0; g < 4; ++g) {
          const int t0 = tb + 8 * g + 4 * h5;
          *(uint2*)(smem + V_OFF + swz(hh2, t0 * 2)) =
            make_uint2(packbf(acc[mi][ni][4*g],   acc[mi][ni][4*g+1]),
                       packbf(acc[mi][ni][4*g+2], acc[mi][ni][4*g+3]));
        }
      }
    }
  }
  __syncthreads();

  //========================= phase 2: S^T = K@Q^T, causal softmax =========================
  const int mt2 = wv & 1;                  // s-half (64 keys)
  const int tq  = (wv >> 1) * 32 + l31;    // this lane's query column
  f32x16 sac[2];
#pragma unroll
  for (int ts2 = 0; ts2 < 2; ++ts2)
#pragma unroll
    for (int r = 0; r < 16; ++r) sac[ts2][r] = 0.f;

#pragma unroll
  for (int ks = 0; ks < 5; ++ks) {         // head-dim = 80 (zeros in 75..79)
    const bh8 qf = *(const bh8*)(smem + Q_OFF + ks * 4096 + tq * 32 + h5 * 16);
#pragma unroll
    for (int ts2 = 0; ts2 < 2; ++ts2) {
      const int sr = (mt2 * 2 + ts2) * 32 + l31;
      const bh8 kf = *(const bh8*)(smem + K_OFF + ks * 4096 + sr * 32 + h5 * 16);
      sac[ts2] = __builtin_amdgcn_mfma_f32_32x32x16_bf16(kf, qf, sac[ts2], 0, 0, 0);
    }
  }

  float pvv[32];
  float vmax = -INFINITY;
  const float scl = 0.040824829046386302f;   // 600^-0.5 (reference scales by C)
#pragma unroll
  for (int ts2 = 0; ts2 < 2; ++ts2) {
    const int st = (mt2 * 2 + ts2) * 32;
#pragma unroll
    for (int r = 0; r < 16; ++r) {
      const int s = st + (r & 3) + 8 * (r >> 2) + 4 * h5;
      float v = sac[ts2][r] * scl;
      v = (s <= tq) ? v : -INFINITY;
      pvv[ts2 * 16 + r] = v;
      vmax = fmaxf(vmax, v);
    }
  }
  vmax = fmaxf(vmax, __shfl_xor(vmax, 32)); // combine half-waves -> partial over 64 keys
  float* pmb = (float*)(smem + PM_OFF);
  float* psb = (float*)(smem + PS_OFF);
  if (h5 == 0) pmb[mt2 * 128 + tq] = vmax;   // XA region is dead; safe before barrier
  __syncthreads();
  const float mrow = fmaxf(pmb[tq], pmb[128 + tq]);
  float sum = 0.f;
#pragma unroll
  for (int i = 0; i < 32; ++i) {
    const float p = bfrt(__expf(pvv[i] - mrow));  // round to bf16 so denom matches numerator
    pvv[i] = p;
    sum += p;
  }
  sum += __shfl_xor(sum, 32);
  if (h5 == 0) psb[mt2 * 128 + tq] = sum;
  // write P half-0 (s<64): only mt2==0 waves own those s values
  if (mt2 == 0) {
#pragma unroll
    for (int ts2 = 0; ts2 < 2; ++ts2) {
#pragma unroll
      for (int g = 0; g < 4; ++g) {
        const int sl = ts2 * 32 + 8 * g + 4 * h5;   // local s in [0,64)
        *(uint2*)(smem + P_OFF + pswz(tq, sl * 2)) =
          make_uint2(packbf(pvv[ts2*16+4*g],   pvv[ts2*16+4*g+1]),
                     packbf(pvv[ts2*16+4*g+2], pvv[ts2*16+4*g+3]));
      }
    }
  }
  __syncthreads();

  //========================= phase 3: O = P@V in two s-halves =========================
  const int l15   = lane & 15;
  const int q4    = lane >> 4;
  const int trow0 = wv * 16;               // wave owns 16 query rows
  f32x4 oac[5];
#pragma unroll
  for (int nt = 0; nt < 5; ++nt)
#pragma unroll
    for (int r = 0; r < 4; ++r) oac[nt][r] = 0.f;

#pragma unroll
  for (int ksl = 0; ksl < 2; ++ksl) {      // s 0..63
    const int kb = ksl * 64 + q4 * 16;
    const bh8 pf = *(const bh8*)(smem + P_OFF + pswz(trow0 + l15, kb));
#pragma unroll
    for (int nt = 0; nt < 5; ++nt) {
      const bh8 vf = *(const bh8*)(smem + V_OFF + swz(nt * 16 + l15, kb));
      oac[nt] = __builtin_amdgcn_mfma_f32_16x16x32_bf16(pf, vf, oac[nt], 0, 0, 0);
    }
  }
  __syncthreads();
  // write P half-1 (s in [64,128)): mt2==1 waves own those s values
  if (mt2 == 1) {
#pragma unroll
    for (int ts2 = 0; ts2 < 2; ++ts2) {
#pragma unroll
      for (int g = 0; g < 4; ++g) {
        const int sl = ts2 * 32 + 8 * g + 4 * h5;
        *(uint2*)(smem + P_OFF + pswz(tq, sl * 2)) =
          make_uint2(packbf(pvv[ts2*16+4*g],   pvv[ts2*16+4*g+1]),
                     packbf(pvv[ts2*16+4*g+2], pvv[ts2*16+4*g+3]));
      }
    }
  }
  __syncthreads();
#pragma unroll
  for (int ksl = 0; ksl < 2; ++ksl) {      // s 64..127
    const int kb = ksl * 64 + q4 * 16;
    const bh8 pf = *(const bh8*)(smem + P_OFF + pswz(trow0 + l15, kb));
#pragma unroll
    for (int nt = 0; nt < 5; ++nt) {
      const bh8 vf = *(const bh8*)(smem + V_OFF + swz(nt * 16 + l15, 128 + kb));
      oac[nt] = __builtin_amdgcn_mfma_f32_16x16x32_bf16(pf, vf, oac[nt], 0, 0, 0);
    }
  }

  const float* psf = (const float*)(smem + PS_OFF);
  float rinv[4];
#pragma unroll
  for (int r = 0; r < 4; ++r) {
    const int t = trow0 + q4 * 4 + r;
    rinv[r] = 1.0f / (psf[t] + psf[128 + t]);
  }
  float* ob = out + (size_t)b * (TT * HH);
#pragma unroll
  for (int nt = 0; nt < 5; ++nt) {
    const int h = nt * 16 + l15;
    if (h < HH) {
#pragma unroll
      for (int r = 0; r < 4; ++r) {
        const int t = trow0 + q4 * 4 + r;
        ob[t * HH + h] = oac[nt][r] * rinv[r];
      }
    }
  }
}

extern "C" void kernel_launch(void* const* d_in, const int* in_sizes, int n_in,
                              void* d_out, int out_size, void* d_ws, size_t ws_size,
                              hipStream_t stream) {
  (void)in_sizes; (void)n_in; (void)out_size; (void)ws_size;
  const float* x  = (const float*)d_in[0];
  const float* Wq = (const float*)d_in[1];
  const float* Wk = (const float*)d_in[2];
  const float* Wv = (const float*)d_in[3];
  uint16_t* wpack = (uint16_t*)d_ws;       // 38*256*16*2 = 311,296 B
  float* out = (float*)d_out;
  pack_w_kernel<<<38, 512, 0, stream>>>(Wq, Wk, Wv, wpack);
  head_kernel<<<512, 512, 0, stream>>>(x, wpack, out);
}